// Round 1
// baseline (559.346 us; speedup 1.0000x reference)
//
#include <hip/hip_runtime.h>
#include <cmath>

typedef __bf16 bf16;
typedef __bf16 bf16x8 __attribute__((ext_vector_type(8)));
typedef __bf16 bf16x4 __attribute__((ext_vector_type(4)));
typedef float f32x4 __attribute__((ext_vector_type(4)));

#define MAXNORM 0.99999f      // (1-EPS)/sqrt(C), C=1, EPS=1e-5
#define ATH_CLIP 0.9999999f   // 1-1e-7 artanh clip
#define MINN 1e-15f

// async global->LDS, 16B per lane. LDS dest is wave-uniform base + lane*16,
// so per-lane lds ptrs MUST be contiguous in lane order (they are: t*16B).
__device__ __forceinline__ void g2l16(const void* g, void* l) {
  __builtin_amdgcn_global_load_lds(
      (const __attribute__((address_space(1))) void*)g,
      (__attribute__((address_space(3))) void*)l, 16, 0, 0);
}

// block-wide (256 thr) sum-reduce of two floats; result broadcast to all threads
__device__ __forceinline__ void reduce2(float& a, float& b) {
  __shared__ float sr[8];
  #pragma unroll
  for (int off = 32; off > 0; off >>= 1) {
    a += __shfl_down(a, off, 64);
    b += __shfl_down(b, off, 64);
  }
  int w = threadIdx.x >> 6;
  if ((threadIdx.x & 63) == 0) { sr[w] = a; sr[4 + w] = b; }
  __syncthreads();
  a = sr[0] + sr[1] + sr[2] + sr[3];
  b = sr[4] + sr[5] + sr[6] + sr[7];
  __syncthreads();
}

// fused prep: [0, convBlocks) -> W cast, [convBlocks, convBlocks+Bm) -> x rows,
// last block -> bias expmap0. Branch is block-uniform (no divergence cost).
__global__ __launch_bounds__(256) void prep_all(
    const float* __restrict__ W, bf16* __restrict__ Wb, long nw, int convBlocks,
    const float* __restrict__ x, bf16* __restrict__ xb, float* __restrict__ q,
    int IN, int Bm, const float* __restrict__ bias, float* __restrict__ y,
    float* __restrict__ y2, int OUT) {
  int t = threadIdx.x;
  int b = blockIdx.x;
  if (b < convBlocks) {
    // ---- W fp32 -> bf16, 8 elems/thread ----
    long i = ((long)b * 256 + t) * 8;
    if (i + 8 <= nw) {
      float4 a = *(const float4*)(W + i);
      float4 c = *(const float4*)(W + i + 4);
      bf16x8 o;
      o[0] = (bf16)a.x; o[1] = (bf16)a.y; o[2] = (bf16)a.z; o[3] = (bf16)a.w;
      o[4] = (bf16)c.x; o[5] = (bf16)c.y; o[6] = (bf16)c.z; o[7] = (bf16)c.w;
      *(bf16x8*)(Wb + i) = o;
    }
  } else if (b < convBlocks + Bm) {
    // ---- per-row: project x, cast->bf16, q = artanh(xn)/xn (IN==4096) ----
    int row = b - convBlocks;
    const float4* xr = (const float4*)(x + (size_t)row * IN);
    float4 v[4];
    float ss = 0.f;
    #pragma unroll
    for (int ii = 0; ii < 4; ii++) {
      float4 a = xr[ii * 256 + t];
      v[ii] = a;
      ss += a.x * a.x + a.y * a.y + a.z * a.z + a.w * a.w;
    }
    float d = 0.f;
    reduce2(ss, d);
    float nrm = sqrtf(ss);
    float s = 1.f, xn = fmaxf(nrm, MINN);
    if (nrm > MAXNORM) { s = MAXNORM / nrm; xn = MAXNORM; }
    if (t == 0) q[row] = atanhf(fminf(xn, ATH_CLIP)) / xn;
    bf16* xo = xb + (size_t)row * IN;
    #pragma unroll
    for (int ii = 0; ii < 4; ii++) {
      float4 a = v[ii];
      bf16x4 o;
      o[0] = (bf16)(a.x * s); o[1] = (bf16)(a.y * s);
      o[2] = (bf16)(a.z * s); o[3] = (bf16)(a.w * s);
      *(bf16x4*)(xo + (size_t)(ii * 256 + t) * 4) = o;
    }
  } else {
    // ---- y = expmap0(bias), y2 = |y|^2 ----
    int n4 = OUT >> 2;
    float ss = 0.f;
    for (int i = t; i < n4; i += 256) {
      float4 v = ((const float4*)bias)[i];
      ss += v.x * v.x + v.y * v.y + v.z * v.z + v.w * v.w;
    }
    float d = 0.f;
    reduce2(ss, d);
    float un = fmaxf(sqrtf(ss), MINN);
    float sc = tanhf(un) / un;
    for (int i = t; i < n4; i += 256) {
      float4 v = ((const float4*)bias)[i];
      float4 o;
      o.x = v.x * sc; o.y = v.y * sc; o.z = v.z * sc; o.w = v.w * sc;
      ((float4*)y)[i] = o;
    }
    if (t == 0) *y2 = sc * sc * ss;
  }
}

// ============================================================================
// 256x256 8-phase GEMM (guide S5 template, T2+T3+T4+T5+T1).
// C[m,n] = sum_k A[m,k]*B[n,k]; A:[M,K] bf16 row-major, B:[N,K] bf16 row-major.
// 8 waves (2M x 4N), per-wave 128x64 out = 8x4 frags of 16x16, BK=64.
// LDS 128 KiB: 2 buffers x (A 256x64 + B 256x64) bf16. 1 block/CU, 2 waves/SIMD.
// Swizzle: stored slot s = chunk ^ (row&7) at 16B granule within 128B rows
// (proven 2-way-free scheme from the 128^2 kernel), achieved by pre-swizzling
// the per-lane GLOBAL source and keeping LDS linear (g2l16 constraint, m104).
//
// Phase ledger (per K-tile t, cur=t&1), each phase = {ds_read, stage, bar,
// lgkmcnt(0), 16 MFMA @prio1, bar}:
//  p1: read all 8 B-frags + A rows 0-31 (12 ds_reads); stage A-tail(t+1)->buf^1
//      (its readers = (t-1).p3/p4, retired at (t-1).p4 end-barrier)
//  p2: read A rows 32-63;  stage B-half0(t+2)->buf  (B fully read in p1)
//  p3: read A rows 64-95;  stage B-half1(t+2)->buf
//  p4: read A rows 96-127; stage A-head(t+2)->buf   (rows read in p1/p2);
//      s_waitcnt vmcnt(6) -> retires through A-tail(t+1) => K-tile t+1 fully
//      resident; B0/B1/A-head(t+2) = 6 loads stay in flight across barriers.
// Prologue: 8 loads (tile0) + 6 loads (tile1 minus A-tail), vmcnt(6), barrier.
// Guards (t+1<NT, t+2<NT) are block-uniform; tail iterations drain vmcnt(0).
// ============================================================================
#define FENCE() asm volatile("" ::: "memory")

template <int Q>
__device__ __forceinline__ void rda(bf16x8 (&af)[2][2], const bf16* aL, int d1) {
  #pragma unroll
  for (int ii = 0; ii < 2; ++ii) {
    const bf16* p = aL + (2 * Q + ii) * 1024;
    af[ii][0] = *(const bf16x8*)p;
    af[ii][1] = *(const bf16x8*)(p + d1);
  }
}

template <int Q>
__device__ __forceinline__ void mfmaq(f32x4 (&acc)[8][4], const bf16x8 (&af)[2][2],
                                      const bf16x8 (&bfr)[4][2]) {
  __builtin_amdgcn_s_setprio(1);
  #pragma unroll
  for (int ii = 0; ii < 2; ++ii)
    #pragma unroll
    for (int j = 0; j < 4; ++j) {
      acc[2 * Q + ii][j] = __builtin_amdgcn_mfma_f32_16x16x32_bf16(
          af[ii][0], bfr[j][0], acc[2 * Q + ii][j], 0, 0, 0);
      acc[2 * Q + ii][j] = __builtin_amdgcn_mfma_f32_16x16x32_bf16(
          af[ii][1], bfr[j][1], acc[2 * Q + ii][j], 0, 0, 0);
    }
  __builtin_amdgcn_s_setprio(0);
}

__global__ __launch_bounds__(512, 2) void gemm256(const bf16* __restrict__ A,
                                                  const bf16* __restrict__ B,
                                                  float* __restrict__ C, int K,
                                                  int N, int nbx) {
  __shared__ __align__(16) bf16 sA[2][256 * 64];
  __shared__ __align__(16) bf16 sB[2][256 * 64];
  int t = threadIdx.x;
  // T1: bijective XCD swizzle (grid is a multiple of 8 here: 512 blocks).
  int nwg = gridDim.x, orig = blockIdx.x;
  int swz = ((nwg & 7) == 0) ? ((orig & 7) * (nwg >> 3) + (orig >> 3)) : orig;
  int bx = swz % nbx, by = swz / nbx;
  int m0 = by * 256, n0 = bx * 256;

  // staging: thread t handles global row (base + t>>3), 16B chunk (t&7)^(row&7)
  int grow = t >> 3;
  int gseg = (t & 7) ^ (grow & 7);
  const bf16* Ag = A + (size_t)(m0 + grow) * K + gseg * 8;
  const bf16* Bg = B + (size_t)(n0 + grow) * K + gseg * 8;
  size_t r64 = (size_t)64 * K;  // 64-row stride (elements)
  bf16* lA = &sA[0][0];
  bf16* lB = &sB[0][0];
  // (p,h,rg): buffer p, 128-row half h, 64-row group rg
  auto stA = [&](int p, int h, int rg, int kt) {
    g2l16(Ag + (size_t)(2 * h + rg) * r64 + kt * 64,
          lA + p * 16384 + h * 8192 + rg * 4096 + t * 8);
  };
  auto stB = [&](int p, int h, int rg, int kt) {
    g2l16(Bg + (size_t)(2 * h + rg) * r64 + kt * 64,
          lB + p * 16384 + h * 8192 + rg * 4096 + t * 8);
  };

  int lane = t & 63, w = t >> 6;
  int quad = lane >> 4, lrow = lane & 15;
  int wm = w >> 2, wn = w & 3;            // 2 x 4 wave grid
  int s0 = quad ^ (lrow & 7);             // de-swizzled 16B slot, k-half 0
  int d1 = 32 - ((s0 & 4) << 4);          // element delta to k-half 1 slot
  int NT = K >> 6;

  // ---- prologue: tile0 fully + tile1 minus A-tail ----
  stB(0, 0, 0, 0); stB(0, 0, 1, 0); stB(0, 1, 0, 0); stB(0, 1, 1, 0);
  stA(0, 0, 0, 0); stA(0, 1, 0, 0); stA(0, 0, 1, 0); stA(0, 1, 1, 0);
  if (NT > 1) {
    stB(1, 0, 0, 1); stB(1, 0, 1, 1); stB(1, 1, 0, 1); stB(1, 1, 1, 1);
    stA(1, 0, 0, 1); stA(1, 1, 0, 1);
    asm volatile("s_waitcnt vmcnt(6)" ::: "memory");
  } else {
    asm volatile("s_waitcnt vmcnt(0)" ::: "memory");
  }
  __builtin_amdgcn_sched_barrier(0);
  FENCE(); __builtin_amdgcn_s_barrier(); FENCE();

  f32x4 acc[8][4];
  #pragma unroll
  for (int i = 0; i < 8; ++i)
    #pragma unroll
    for (int j = 0; j < 4; ++j) acc[i][j] = (f32x4)0.f;

  const int aoff = wm * 8192 + lrow * 64 + s0 * 8;                    // +i*1024
  const int boff = (wn >> 1) * 8192 + (wn & 1) * 4096 + lrow * 64 + s0 * 8;

#define PBAR()                                          \
  FENCE(); __builtin_amdgcn_s_barrier();                \
  asm volatile("s_waitcnt lgkmcnt(0)" ::: "memory");    \
  __builtin_amdgcn_sched_barrier(0)
#define EBAR()                                          \
  __builtin_amdgcn_sched_barrier(0); FENCE();           \
  __builtin_amdgcn_s_barrier(); FENCE()

  bf16x8 bfr[4][2], af[2][2];
  for (int kt = 0; kt < NT; ++kt) {
    int cur = kt & 1, nxt = cur ^ 1;
    const bf16* aL = lA + cur * 16384 + aoff;
    const bf16* bL = lB + cur * 16384 + boff;
    bool pf1 = (kt + 1 < NT), pf2 = (kt + 2 < NT);
    // ---- phase 1: all B-frags + A quad0 (12 ds_reads); stage A-tail(t+1)
    #pragma unroll
    for (int j = 0; j < 4; ++j) {
      const bf16* bp = bL + j * 1024;
      bfr[j][0] = *(const bf16x8*)bp;
      bfr[j][1] = *(const bf16x8*)(bp + d1);
    }
    rda<0>(af, aL, d1);
    if (pf1) { stA(nxt, 0, 1, kt + 1); stA(nxt, 1, 1, kt + 1); }
    PBAR(); mfmaq<0>(acc, af, bfr); EBAR();
    // ---- phase 2: A quad1; stage B-half0(t+2)
    rda<1>(af, aL, d1);
    if (pf2) { stB(cur, 0, 0, kt + 2); stB(cur, 0, 1, kt + 2); }
    PBAR(); mfmaq<1>(acc, af, bfr); EBAR();
    // ---- phase 3: A quad2; stage B-half1(t+2)
    rda<2>(af, aL, d1);
    if (pf2) { stB(cur, 1, 0, kt + 2); stB(cur, 1, 1, kt + 2); }
    PBAR(); mfmaq<2>(acc, af, bfr); EBAR();
    // ---- phase 4: A quad3; stage A-head(t+2); counted vmcnt, never 0 mid-loop
    rda<3>(af, aL, d1);
    if (pf2) { stA(cur, 0, 0, kt + 2); stA(cur, 1, 0, kt + 2); }
    PBAR(); mfmaq<3>(acc, af, bfr);
    if (pf2) asm volatile("s_waitcnt vmcnt(6)" ::: "memory");
    else     asm volatile("s_waitcnt vmcnt(0)" ::: "memory");
    EBAR();
  }
  // C/D layout: n = lane&15, m = quad*4 + reg (m89/m91-verified mapping)
  int row0 = m0 + wm * 128 + quad * 4;
  int col0 = n0 + wn * 64 + lrow;
  #pragma unroll
  for (int i = 0; i < 8; ++i) {
    #pragma unroll
    for (int r = 0; r < 4; ++r) {
      float* Cr = C + (size_t)(row0 + i * 16 + r) * N + col0;
      #pragma unroll
      for (int j = 0; j < 4; ++j) Cr[j * 16] = acc[i][j][r];
    }
  }
}

// Fallback 128x128 GEMM (proven; used only for shapes not divisible by 256).
__global__ __launch_bounds__(256, 4) void gemm_bt(const bf16* __restrict__ A,
                                                  const bf16* __restrict__ B,
                                                  float* __restrict__ C, int K,
                                                  int N) {
  __shared__ __align__(16) bf16 sA[128 * 64];
  __shared__ __align__(16) bf16 sB[128 * 64];
  int t = threadIdx.x;
  int m0 = blockIdx.y * 128, n0 = blockIdx.x * 128;
  int grow = t >> 3;
  int gseg = (t & 7) ^ (grow & 7);
  const bf16* Ag = A + (size_t)(m0 + grow) * K + gseg * 8;
  const bf16* Bg = B + (size_t)(n0 + grow) * K + gseg * 8;
  bf16* lA = sA + t * 8;
  bf16* lB = sB + t * 8;
  size_t cstep = (size_t)32 * K;

  int lane = t & 63, w = t >> 6;
  int quad = lane >> 4, lrow = lane & 15;
  int wm = (w >> 1) * 64, wn = (w & 1) * 64;
  int s0 = quad ^ (lrow & 7);
  int d1 = 32 - ((s0 & 4) << 4);
  const bf16* pA[4];
  const bf16* pB[4];
  #pragma unroll
  for (int i = 0; i < 4; i++) {
    pA[i] = sA + (wm + i * 16 + lrow) * 64 + s0 * 8;
    pB[i] = sB + (wn + i * 16 + lrow) * 64 + s0 * 8;
  }
  f32x4 acc[4][4];
  #pragma unroll
  for (int i = 0; i < 4; i++)
    #pragma unroll
    for (int j = 0; j < 4; j++) acc[i][j] = (f32x4)0.f;

  for (int k0 = 0; k0 < K; k0 += 64) {
    g2l16(Ag + k0, lA);
    g2l16(Ag + cstep + k0, lA + 2048);
    g2l16(Ag + 2 * cstep + k0, lA + 4096);
    g2l16(Ag + 3 * cstep + k0, lA + 6144);
    g2l16(Bg + k0, lB);
    g2l16(Bg + cstep + k0, lB + 2048);
    g2l16(Bg + 2 * cstep + k0, lB + 4096);
    g2l16(Bg + 3 * cstep + k0, lB + 6144);
    __syncthreads();
    #pragma unroll
    for (int h = 0; h < 2; h++) {
      int d = h ? d1 : 0;
      bf16x8 af[4], bfr[4];
      #pragma unroll
      for (int i = 0; i < 4; i++) af[i] = *(const bf16x8*)(pA[i] + d);
      #pragma unroll
      for (int j = 0; j < 4; j++) bfr[j] = *(const bf16x8*)(pB[j] + d);
      #pragma unroll
      for (int i = 0; i < 4; i++)
        #pragma unroll
        for (int j = 0; j < 4; j++)
          acc[i][j] = __builtin_amdgcn_mfma_f32_16x16x32_bf16(af[i], bfr[j],
                                                              acc[i][j], 0, 0, 0);
    }
    __syncthreads();
  }
  #pragma unroll
  for (int i = 0; i < 4; i++) {
    #pragma unroll
    for (int r = 0; r < 4; r++) {
      int row = m0 + wm + i * 16 + quad * 4 + r;
      float* Cr = C + (size_t)row * N + n0 + wn + lrow;
      #pragma unroll
      for (int j = 0; j < 4; j++) Cr[j * 16] = acc[i][j][r];
    }
  }
}

// per-row: Smm=sum mx^2, Smy=sum mx*y -> scalars -> out = s*(A*mx + B*y)
// in-place on d_out. hardcoded for N == 4096.
__global__ __launch_bounds__(256) void finish(float* __restrict__ out,
                                              const float* __restrict__ y,
                                              const float* __restrict__ y2p,
                                              const float* __restrict__ q,
                                              int N) {
  int row = blockIdx.x, t = threadIdx.x;
  float4* orow = (float4*)(out + (size_t)row * N);
  const float4* yv = (const float4*)y;
  float smm = 0.f, smy = 0.f;
  float4 rm[4], ry[4];
  #pragma unroll
  for (int ii = 0; ii < 4; ii++) {
    float4 a = orow[ii * 256 + t];
    float4 b = yv[ii * 256 + t];
    rm[ii] = a;
    ry[ii] = b;
    smm += a.x * a.x + a.y * a.y + a.z * a.z + a.w * a.w;
    smy += a.x * b.x + a.y * b.y + a.z * b.z + a.w * b.w;
  }
  reduce2(smm, smy);
  float y2 = *y2p;
  float mxn = fmaxf(sqrtf(smm), MINN);
  float r = tanhf(mxn * q[row]);
  float alpha = (smm == 0.f) ? 0.f : r / mxn;
  float x2 = (smm == 0.f) ? 0.f : r * r;
  float xy = alpha * smy;
  float c1 = 1.f + 2.f * xy + y2;
  float den = fmaxf(1.f + 2.f * xy + x2 * y2, MINN);
  float Af = c1 * alpha / den;
  float Bf = (1.f - x2) / den;
  float on2 = Af * Af * smm + 2.f * Af * Bf * smy + Bf * Bf * y2;
  float on = sqrtf(fmaxf(on2, 0.f));
  float s = (on > MAXNORM) ? MAXNORM / fmaxf(on, MINN) : 1.f;
  float As = Af * s, Bs = Bf * s;
  #pragma unroll
  for (int ii = 0; ii < 4; ii++) {
    float4 a = rm[ii], b = ry[ii];
    float4 o;
    o.x = As * a.x + Bs * b.x;
    o.y = As * a.y + Bs * b.y;
    o.z = As * a.z + Bs * b.z;
    o.w = As * a.w + Bs * b.w;
    orow[ii * 256 + t] = o;
  }
}

extern "C" void kernel_launch(void* const* d_in, const int* in_sizes, int n_in,
                              void* d_out, int out_size, void* d_ws,
                              size_t ws_size, hipStream_t stream) {
  const float* x = (const float*)d_in[0];
  const float* W = (const float*)d_in[1];
  const float* bias = (const float*)d_in[2];
  float* out = (float*)d_out;
  int OUT = in_sizes[2];
  int IN = in_sizes[1] / OUT;
  int Bm = in_sizes[0] / IN;

  // workspace carve: Xb (B*IN bf16) | Wb (OUT*IN bf16) | q (B f32) | y (OUT f32) | y2 (1 f32)
  char* ws = (char*)d_ws;
  size_t xb_bytes = (size_t)Bm * IN * sizeof(bf16);
  size_t wb_bytes = (size_t)OUT * IN * sizeof(bf16);
  bf16* Xb = (bf16*)ws;
  bf16* Wb = (bf16*)(ws + xb_bytes);
  float* q = (float*)(ws + xb_bytes + wb_bytes);
  float* y = q + Bm;
  float* y2 = y + OUT;

  long nw = (long)OUT * IN;
  int convBlocks = (int)((nw / 8 + 255) / 256);
  prep_all<<<convBlocks + Bm + 1, 256, 0, stream>>>(
      W, Wb, nw, convBlocks, x, Xb, q, IN, Bm, bias, y, y2, OUT);
  if ((OUT % 256 == 0) && (Bm % 256 == 0) && (IN % 64 == 0)) {
    int nbx = OUT / 256;
    gemm256<<<nbx * (Bm / 256), 512, 0, stream>>>(Xb, Wb, out, IN, OUT, nbx);
  } else {
    gemm_bt<<<dim3(OUT / 128, Bm / 128), 256, 0, stream>>>(Xb, Wb, out, IN, OUT);
  }
  finish<<<Bm, 256, 0, stream>>>(out, y, y2, q, OUT);
}